// Round 1
// baseline (3059.044 us; speedup 1.0000x reference)
//
#include <hip/hip_runtime.h>

#define F_IN 256
#define F_HID 64

// ---------------- GEMM: h = x @ W  (M x 256) @ (256 x 64) -> (M x 64) --------
__global__ __launch_bounds__(256) void gemm_xw_kernel(
    const float* __restrict__ x, const float* __restrict__ W,
    float* __restrict__ h, int M) {
  __shared__ float As[32][68];   // [k][m], padded to 68 to break write conflicts
  __shared__ float Bs[32][64];   // [k][n]
  const int t = threadIdx.x;
  const int brow = blockIdx.x * 64;
  const int tc = t & 15;   // col group -> cols tc*4 .. tc*4+3
  const int tr = t >> 4;   // row group -> rows tr*4 .. tr*4+3
  float acc[4][4] = {{0.f}};

  for (int k0 = 0; k0 < F_IN; k0 += 32) {
    // stage A tile (transposed): As[k][m] = x[brow+m][k0+k]
    {
      const int m = t >> 3;
      const int kq = (t & 7) << 2;
#pragma unroll
      for (int half = 0; half < 2; ++half) {
        const int mm = m + half * 32;
        const int row = brow + mm;
        float4 v = make_float4(0.f, 0.f, 0.f, 0.f);
        if (row < M) v = *(const float4*)(x + (size_t)row * F_IN + k0 + kq);
        As[kq + 0][mm] = v.x;
        As[kq + 1][mm] = v.y;
        As[kq + 2][mm] = v.z;
        As[kq + 3][mm] = v.w;
      }
      // stage B tile: Bs[k][n] = W[k0+k][n]
#pragma unroll
      for (int half = 0; half < 2; ++half) {
        const int i = t + half * 256;
        const int kb = i >> 4;
        const int nq = (i & 15) << 2;
        *(float4*)&Bs[kb][nq] = *(const float4*)(W + (size_t)(k0 + kb) * 64 + nq);
      }
    }
    __syncthreads();
#pragma unroll
    for (int k = 0; k < 32; ++k) {
      const float4 a = *(const float4*)&As[k][tr << 2];
      const float4 b = *(const float4*)&Bs[k][tc << 2];
      const float av[4] = {a.x, a.y, a.z, a.w};
      const float bv[4] = {b.x, b.y, b.z, b.w};
#pragma unroll
      for (int i = 0; i < 4; ++i)
#pragma unroll
        for (int j = 0; j < 4; ++j) acc[i][j] += av[i] * bv[j];
    }
    __syncthreads();
  }
#pragma unroll
  for (int i = 0; i < 4; ++i) {
    const int row = brow + (tr << 2) + i;
    if (row < M) {
      float4 v = make_float4(acc[i][0], acc[i][1], acc[i][2], acc[i][3]);
      *(float4*)(h + (size_t)row * 64 + (tc << 2)) = v;
    }
  }
}

// ---------------- degree count over dst --------------------------------------
__global__ __launch_bounds__(256) void deg_kernel(
    const int* __restrict__ dst_arr, int* __restrict__ degi, int E) {
  const int e = blockIdx.x * 256 + threadIdx.x;
  if (e < E) atomicAdd(&degi[dst_arr[e]], 1);
}

__global__ __launch_bounds__(256) void dinv_kernel(
    const int* __restrict__ degi, float* __restrict__ dinv, int N) {
  const int i = blockIdx.x * 256 + threadIdx.x;
  if (i < N) dinv[i] = rsqrtf((float)(degi[i] + 1));  // +1 self-loop
}

// ---------------- edge aggregation: agg[dst] += norm * h[src] ----------------
__global__ __launch_bounds__(256) void aggregate_kernel(
    const float* __restrict__ h, const int* __restrict__ src_arr,
    const int* __restrict__ dst_arr, const float* __restrict__ dinv,
    float* __restrict__ agg, int E) {
  const int tid = blockIdx.x * 256 + threadIdx.x;
  const int e = tid >> 4;        // 16 threads per edge
  if (e >= E) return;
  const int q = (tid & 15) << 2; // feature quad
  const int s = src_arr[e];
  const int d = dst_arr[e];
  const float n = dinv[s] * dinv[d];
  const float4 v = *(const float4*)(h + (size_t)s * 64 + q);
  float* ap = agg + (size_t)d * 64 + q;
  unsafeAtomicAdd(ap + 0, v.x * n);
  unsafeAtomicAdd(ap + 1, v.y * n);
  unsafeAtomicAdd(ap + 2, v.z * n);
  unsafeAtomicAdd(ap + 3, v.w * n);
}

// ---------------- fused epilogue + MLP ---------------------------------------
__global__ __launch_bounds__(256) void mlp_kernel(
    const float* __restrict__ agg, const float* __restrict__ h,
    const float* __restrict__ dinv, const float* __restrict__ bg,
    const float* __restrict__ W1, const float* __restrict__ b1,
    const float* __restrict__ W2, const float* __restrict__ b2,
    const float* __restrict__ W3, const float* __restrict__ b3,
    float* __restrict__ out, int N) {
  __shared__ float W1T[32][64];  // W1T[j][k] = W1[k][j]
  __shared__ float W2T[16][32];
  __shared__ float W3T[10][16];
  __shared__ float b1s[32], b2s[16], b3s[10], bgs[64];
  const int t = threadIdx.x;
  for (int i = t; i < 2048; i += 256) W1T[i >> 6][i & 63] = W1[(i & 63) * 32 + (i >> 6)];
  for (int i = t; i < 512; i += 256)  W2T[i >> 5][i & 31] = W2[(i & 31) * 16 + (i >> 5)];
  for (int i = t; i < 160; i += 256)  W3T[i >> 4][i & 15] = W3[(i & 15) * 10 + (i >> 4)];
  if (t < 64) bgs[t] = bg[t];
  if (t < 32) b1s[t] = b1[t];
  if (t < 16) b2s[t] = b2[t];
  if (t < 10) b3s[t] = b3[t];
  __syncthreads();

  const int node = blockIdx.x * 256 + t;
  if (node >= N) return;
  const float di = dinv[node];
  const float d2 = di * di;

  float g[64];
#pragma unroll
  for (int k = 0; k < 64; k += 4) {
    const float4 a = *(const float4*)(agg + (size_t)node * 64 + k);
    const float4 hv = *(const float4*)(h + (size_t)node * 64 + k);
    g[k + 0] = fmaxf(a.x + d2 * hv.x + bgs[k + 0], 0.f);
    g[k + 1] = fmaxf(a.y + d2 * hv.y + bgs[k + 1], 0.f);
    g[k + 2] = fmaxf(a.z + d2 * hv.z + bgs[k + 2], 0.f);
    g[k + 3] = fmaxf(a.w + d2 * hv.w + bgs[k + 3], 0.f);
  }

  float h1[32];
#pragma unroll
  for (int j = 0; j < 32; ++j) {
    float acc = b1s[j];
#pragma unroll
    for (int k = 0; k < 64; k += 4) {
      const float4 w = *(const float4*)&W1T[j][k];
      acc += g[k] * w.x + g[k + 1] * w.y + g[k + 2] * w.z + g[k + 3] * w.w;
    }
    h1[j] = fmaxf(acc, 0.f);
  }

  float h2[16];
#pragma unroll
  for (int j = 0; j < 16; ++j) {
    float acc = b2s[j];
#pragma unroll
    for (int k = 0; k < 32; k += 4) {
      const float4 w = *(const float4*)&W2T[j][k];
      acc += h1[k] * w.x + h1[k + 1] * w.y + h1[k + 2] * w.z + h1[k + 3] * w.w;
    }
    h2[j] = fmaxf(acc, 0.f);
  }

#pragma unroll
  for (int j = 0; j < 10; ++j) {
    float acc = b3s[j];
#pragma unroll
    for (int k = 0; k < 16; k += 4) {
      const float4 w = *(const float4*)&W3T[j][k];
      acc += h2[k] * w.x + h2[k + 1] * w.y + h2[k + 2] * w.z + h2[k + 3] * w.w;
    }
    out[(size_t)node * 10 + j] = acc;
  }
}

extern "C" void kernel_launch(void* const* d_in, const int* in_sizes, int n_in,
                              void* d_out, int out_size, void* d_ws, size_t ws_size,
                              hipStream_t stream) {
  const float* x     = (const float*)d_in[0];
  const int*   ei    = (const int*)d_in[1];
  const float* W_gcn = (const float*)d_in[2];
  const float* b_gcn = (const float*)d_in[3];
  const float* W1    = (const float*)d_in[4];
  const float* b1    = (const float*)d_in[5];
  const float* W2    = (const float*)d_in[6];
  const float* b2    = (const float*)d_in[7];
  const float* W3    = (const float*)d_in[8];
  const float* b3    = (const float*)d_in[9];
  float* out = (float*)d_out;

  const int N = in_sizes[0] / F_IN;  // 100000 nodes
  const int E = in_sizes[1] / 2;     // 3200000 edges
  const int* src = ei;
  const int* dst = ei + E;

  float* h    = (float*)d_ws;                 // N*64 floats
  float* agg  = h + (size_t)N * 64;           // N*64 floats
  float* dinv = agg + (size_t)N * 64;         // N floats
  int*   degi = (int*)(dinv + N);             // N ints

  hipMemsetAsync(agg, 0, (size_t)N * 64 * sizeof(float), stream);
  hipMemsetAsync(degi, 0, (size_t)N * sizeof(int), stream);

  gemm_xw_kernel<<<(N + 63) / 64, 256, 0, stream>>>(x, W_gcn, h, N);
  deg_kernel<<<(E + 255) / 256, 256, 0, stream>>>(dst, degi, E);
  dinv_kernel<<<(N + 255) / 256, 256, 0, stream>>>(degi, dinv, N);

  const long long aggthreads = (long long)E * 16;
  aggregate_kernel<<<(int)((aggthreads + 255) / 256), 256, 0, stream>>>(
      h, src, dst, dinv, agg, E);

  mlp_kernel<<<(N + 255) / 256, 256, 0, stream>>>(
      agg, h, dinv, b_gcn, W1, b1, W2, b2, W3, b3, out, N);
}

// Round 2
// 746.789 us; speedup vs baseline: 4.0963x; 4.0963x over previous
//
#include <hip/hip_runtime.h>

#define F_IN 256
#define F_HID 64

// ---------------- GEMM: h = x @ W  (M x 256) @ (256 x 64) -> (M x 64) --------
__global__ __launch_bounds__(256) void gemm_xw_kernel(
    const float* __restrict__ x, const float* __restrict__ W,
    float* __restrict__ h, int M) {
  __shared__ float As[32][68];   // [k][m], padded
  __shared__ float Bs[32][64];   // [k][n]
  const int t = threadIdx.x;
  const int brow = blockIdx.x * 64;
  const int tc = t & 15;
  const int tr = t >> 4;
  float acc[4][4] = {{0.f}};

  for (int k0 = 0; k0 < F_IN; k0 += 32) {
    {
      const int m = t >> 3;
      const int kq = (t & 7) << 2;
#pragma unroll
      for (int half = 0; half < 2; ++half) {
        const int mm = m + half * 32;
        const int row = brow + mm;
        float4 v = make_float4(0.f, 0.f, 0.f, 0.f);
        if (row < M) v = *(const float4*)(x + (size_t)row * F_IN + k0 + kq);
        As[kq + 0][mm] = v.x;
        As[kq + 1][mm] = v.y;
        As[kq + 2][mm] = v.z;
        As[kq + 3][mm] = v.w;
      }
#pragma unroll
      for (int half = 0; half < 2; ++half) {
        const int i = t + half * 256;
        const int kb = i >> 4;
        const int nq = (i & 15) << 2;
        *(float4*)&Bs[kb][nq] = *(const float4*)(W + (size_t)(k0 + kb) * 64 + nq);
      }
    }
    __syncthreads();
#pragma unroll
    for (int k = 0; k < 32; ++k) {
      const float4 a = *(const float4*)&As[k][tr << 2];
      const float4 b = *(const float4*)&Bs[k][tc << 2];
      const float av[4] = {a.x, a.y, a.z, a.w};
      const float bv[4] = {b.x, b.y, b.z, b.w};
#pragma unroll
      for (int i = 0; i < 4; ++i)
#pragma unroll
        for (int j = 0; j < 4; ++j) acc[i][j] += av[i] * bv[j];
    }
    __syncthreads();
  }
#pragma unroll
  for (int i = 0; i < 4; ++i) {
    const int row = brow + (tr << 2) + i;
    if (row < M) {
      float4 v = make_float4(acc[i][0], acc[i][1], acc[i][2], acc[i][3]);
      *(float4*)(h + (size_t)row * 64 + (tc << 2)) = v;
    }
  }
}

// ---------------- degree count over dst --------------------------------------
__global__ __launch_bounds__(256) void deg_kernel(
    const int* __restrict__ dst_arr, int* __restrict__ degi, int E) {
  const int e = blockIdx.x * 256 + threadIdx.x;
  if (e < E) atomicAdd(&degi[dst_arr[e]], 1);
}

// ---------------- scan: rowptr = exclusive_scan(deg) -------------------------
__global__ __launch_bounds__(256) void scan_block_kernel(
    const int* __restrict__ degi, int* __restrict__ rowptr,
    int* __restrict__ bsum, int N) {
  __shared__ int s[256];
  const int t = threadIdx.x;
  const int i = blockIdx.x * 256 + t;
  const int v = (i < N) ? degi[i] : 0;
  s[t] = v;
  __syncthreads();
#pragma unroll
  for (int off = 1; off < 256; off <<= 1) {
    int add = 0;
    if (t >= off) add = s[t - off];
    __syncthreads();
    s[t] += add;
    __syncthreads();
  }
  if (i < N) rowptr[i] = s[t] - v;  // exclusive
  if (t == 255) bsum[blockIdx.x] = s[t];
}

__global__ __launch_bounds__(512) void scan_bsum_kernel(int* __restrict__ bsum, int NB) {
  __shared__ int s[512];
  const int t = threadIdx.x;
  const int v = (t < NB) ? bsum[t] : 0;
  s[t] = v;
  __syncthreads();
#pragma unroll
  for (int off = 1; off < 512; off <<= 1) {
    int add = 0;
    if (t >= off) add = s[t - off];
    __syncthreads();
    s[t] += add;
    __syncthreads();
  }
  if (t < NB) bsum[t] = s[t] - v;  // exclusive block offsets
}

__global__ __launch_bounds__(256) void add_offsets_kernel(
    int* __restrict__ rowptr, const int* __restrict__ bsum,
    int* __restrict__ cursor, int N, int E) {
  const int i = blockIdx.x * 256 + threadIdx.x;
  if (i < N) {
    const int r = rowptr[i] + bsum[blockIdx.x];
    rowptr[i] = r;
    cursor[i] = r;
  }
  if (i == 0) rowptr[N] = E;
}

// ---------------- bin edges into CSR: es[pos] = src --------------------------
__global__ __launch_bounds__(256) void bin_kernel(
    const int* __restrict__ src_arr, const int* __restrict__ dst_arr,
    int* __restrict__ cursor, int* __restrict__ es, int E) {
  const int e = blockIdx.x * 256 + threadIdx.x;
  if (e < E) {
    const int d = dst_arr[e];
    const int pos = atomicAdd(&cursor[d], 1);
    es[pos] = src_arr[e];
  }
}

// ---------------- CSR aggregation: one wave per node -------------------------
__global__ __launch_bounds__(256) void agg_csr_kernel(
    const float* __restrict__ h, const int* __restrict__ es,
    const int* __restrict__ rowptr, const float* __restrict__ dinvp,
    float* __restrict__ agg, int N) {
  const int t = threadIdx.x;
  const int node = blockIdx.x * 4 + (t >> 6);
  if (node >= N) return;
  const int lane = t & 63;
  const int slot = lane >> 4;        // 0..3 : edge slot
  const int q = (lane & 15) << 2;    // feature quad
  const int start = rowptr[node];
  const int end = rowptr[node + 1];

  float4 acc = make_float4(0.f, 0.f, 0.f, 0.f);
  for (int i = start + slot; i < end; i += 4) {
    const int s = es[i];
    const float w = dinvp[s];
    const float4 v = *(const float4*)(h + (size_t)s * 64 + q);
    acc.x += w * v.x;
    acc.y += w * v.y;
    acc.z += w * v.z;
    acc.w += w * v.w;
  }
  // reduce across the 4 edge slots (lanes differing in bits 4,5)
  acc.x += __shfl_xor(acc.x, 16, 64);
  acc.y += __shfl_xor(acc.y, 16, 64);
  acc.z += __shfl_xor(acc.z, 16, 64);
  acc.w += __shfl_xor(acc.w, 16, 64);
  acc.x += __shfl_xor(acc.x, 32, 64);
  acc.y += __shfl_xor(acc.y, 32, 64);
  acc.z += __shfl_xor(acc.z, 32, 64);
  acc.w += __shfl_xor(acc.w, 32, 64);

  if (slot == 0) {
    const float wd = dinvp[node];
    float4 o = make_float4(acc.x * wd, acc.y * wd, acc.z * wd, acc.w * wd);
    *(float4*)(agg + (size_t)node * 64 + q) = o;
  }
}

__global__ __launch_bounds__(256) void dinv_kernel(
    const int* __restrict__ degi, float* __restrict__ dinvp, int N) {
  const int i = blockIdx.x * 256 + threadIdx.x;
  if (i < N) dinvp[i] = rsqrtf((float)(degi[i] + 1));  // +1 self-loop
}

// ---------------- fused epilogue + MLP ---------------------------------------
__global__ __launch_bounds__(256) void mlp_kernel(
    const float* __restrict__ agg, const float* __restrict__ h,
    const float* __restrict__ dinvp, const float* __restrict__ bg,
    const float* __restrict__ W1, const float* __restrict__ b1,
    const float* __restrict__ W2, const float* __restrict__ b2,
    const float* __restrict__ W3, const float* __restrict__ b3,
    float* __restrict__ out, int N) {
  __shared__ float W1T[32][64];
  __shared__ float W2T[16][32];
  __shared__ float W3T[10][16];
  __shared__ float b1s[32], b2s[16], b3s[10], bgs[64];
  const int t = threadIdx.x;
  for (int i = t; i < 2048; i += 256) W1T[i >> 6][i & 63] = W1[(i & 63) * 32 + (i >> 6)];
  for (int i = t; i < 512; i += 256)  W2T[i >> 5][i & 31] = W2[(i & 31) * 16 + (i >> 5)];
  for (int i = t; i < 160; i += 256)  W3T[i >> 4][i & 15] = W3[(i & 15) * 10 + (i >> 4)];
  if (t < 64) bgs[t] = bg[t];
  if (t < 32) b1s[t] = b1[t];
  if (t < 16) b2s[t] = b2[t];
  if (t < 10) b3s[t] = b3[t];
  __syncthreads();

  const int node = blockIdx.x * 256 + t;
  if (node >= N) return;
  const float di = dinvp[node];
  const float d2 = di * di;

  float g[64];
#pragma unroll
  for (int k = 0; k < 64; k += 4) {
    const float4 a = *(const float4*)(agg + (size_t)node * 64 + k);
    const float4 hv = *(const float4*)(h + (size_t)node * 64 + k);
    g[k + 0] = fmaxf(a.x + d2 * hv.x + bgs[k + 0], 0.f);
    g[k + 1] = fmaxf(a.y + d2 * hv.y + bgs[k + 1], 0.f);
    g[k + 2] = fmaxf(a.z + d2 * hv.z + bgs[k + 2], 0.f);
    g[k + 3] = fmaxf(a.w + d2 * hv.w + bgs[k + 3], 0.f);
  }

  float h1[32];
#pragma unroll
  for (int j = 0; j < 32; ++j) {
    float acc = b1s[j];
#pragma unroll
    for (int k = 0; k < 64; k += 4) {
      const float4 w = *(const float4*)&W1T[j][k];
      acc += g[k] * w.x + g[k + 1] * w.y + g[k + 2] * w.z + g[k + 3] * w.w;
    }
    h1[j] = fmaxf(acc, 0.f);
  }

  float h2[16];
#pragma unroll
  for (int j = 0; j < 16; ++j) {
    float acc = b2s[j];
#pragma unroll
    for (int k = 0; k < 32; k += 4) {
      const float4 w = *(const float4*)&W2T[j][k];
      acc += h1[k] * w.x + h1[k + 1] * w.y + h1[k + 2] * w.z + h1[k + 3] * w.w;
    }
    h2[j] = fmaxf(acc, 0.f);
  }

#pragma unroll
  for (int j = 0; j < 10; ++j) {
    float acc = b3s[j];
#pragma unroll
    for (int k = 0; k < 16; k += 4) {
      const float4 w = *(const float4*)&W3T[j][k];
      acc += h2[k] * w.x + h2[k + 1] * w.y + h2[k + 2] * w.z + h2[k + 3] * w.w;
    }
    out[(size_t)node * 10 + j] = acc;
  }
}

extern "C" void kernel_launch(void* const* d_in, const int* in_sizes, int n_in,
                              void* d_out, int out_size, void* d_ws, size_t ws_size,
                              hipStream_t stream) {
  const float* x     = (const float*)d_in[0];
  const int*   ei    = (const int*)d_in[1];
  const float* W_gcn = (const float*)d_in[2];
  const float* b_gcn = (const float*)d_in[3];
  const float* W1    = (const float*)d_in[4];
  const float* b1    = (const float*)d_in[5];
  const float* W2    = (const float*)d_in[6];
  const float* b2    = (const float*)d_in[7];
  const float* W3    = (const float*)d_in[8];
  const float* b3    = (const float*)d_in[9];
  float* out = (float*)d_out;

  const int N = in_sizes[0] / F_IN;  // 100000 nodes
  const int E = in_sizes[1] / 2;     // 3200000 edges
  const int* src = ei;
  const int* dst = ei + E;
  const int NB = (N + 255) / 256;    // scan blocks (391 <= 512)

  float* h      = (float*)d_ws;                     // N*64 f
  float* agg    = h + (size_t)N * 64;               // N*64 f
  float* dinvp  = agg + (size_t)N * 64;             // N f
  int*   degi   = (int*)(dinvp + N);                // N i
  int*   rowptr = degi + N;                         // N+1 i
  int*   cursor = rowptr + N + 1;                   // N i
  int*   bsum   = cursor + N;                       // 512 i
  int*   es     = bsum + 512;                       // E i

  hipMemsetAsync(degi, 0, (size_t)N * sizeof(int), stream);

  gemm_xw_kernel<<<(N + 63) / 64, 256, 0, stream>>>(x, W_gcn, h, N);
  deg_kernel<<<(E + 255) / 256, 256, 0, stream>>>(dst, degi, E);

  scan_block_kernel<<<NB, 256, 0, stream>>>(degi, rowptr, bsum, N);
  scan_bsum_kernel<<<1, 512, 0, stream>>>(bsum, NB);
  add_offsets_kernel<<<NB, 256, 0, stream>>>(rowptr, bsum, cursor, N, E);

  bin_kernel<<<(E + 255) / 256, 256, 0, stream>>>(src, dst, cursor, es, E);
  dinv_kernel<<<(N + 255) / 256, 256, 0, stream>>>(degi, dinvp, N);

  agg_csr_kernel<<<(N + 3) / 4, 256, 0, stream>>>(h, es, rowptr, dinvp, agg, N);

  mlp_kernel<<<(N + 255) / 256, 256, 0, stream>>>(
      agg, h, dinvp, b_gcn, W1, b1, W2, b2, W3, b3, out, N);
}